// Round 5
// baseline (5590.541 us; speedup 1.0000x reference)
//
#include <hip/hip_runtime.h>

#define TT 64
#define BB 256
#define HH 1024
#define ZZ 512
#define EE 32

#define NKB0 33   // K=1056 in 32-deep blocks (layer0: h 32 blocks + x 1 block)
#define NKB1 64   // K=2048
#define NKBZ 16   // K=512
#define NKBP 32   // K=1024

#define SLOTSH ((size_t)(HH / 16) * BB * 16)   // shorts per tiled h slot = 262144 (512 KB)

// bar[] word map (all on separate 128B lines): leaves 0..15 at i*32, root 16*32,
// flag 17*32, claim counters (18+x)*32, overflow 26*32
#define BAR_ROOT (16 * 32)
#define BAR_FLAG (17 * 32)
#define BAR_CNT  (18 * 32)
#define BAR_OVF  (26 * 32)

typedef __attribute__((ext_vector_type(8))) short short8;
typedef __attribute__((ext_vector_type(4))) float f4;

__device__ __forceinline__ f4 mfma16(short8 a, short8 b, f4 c) {
  return __builtin_amdgcn_mfma_f32_16x16x32_bf16(a, b, c, 0, 0, 0);
}

__device__ __forceinline__ unsigned short f2bf(float f) {
  unsigned u = __builtin_bit_cast(unsigned, f);
  u = u + 0x7fffu + ((u >> 16) & 1u);   // RNE; inputs are finite
  return (unsigned short)(u >> 16);
}

__device__ __forceinline__ float sigm(float x) { return 1.0f / (1.0f + __expf(-x)); }
__device__ __forceinline__ float tanh_f(float x) { return 1.0f - 2.0f / (__expf(2.0f * x) + 1.0f); }

__device__ __forceinline__ short8 ld16(const short* p) { return *(const short8*)p; }

// Agent-scope relaxed 16B load as 2x8B atomics -> global_load_dwordx2 sc1
// (L2-bypass, device-coherent, vmcnt-tracked so the compiler can pipeline it).
__device__ __forceinline__ short8 ld16_byp(const short* p) {
  union { unsigned long long u[2]; short8 v; } t;
  t.u[0] = __hip_atomic_load((const unsigned long long*)p, __ATOMIC_RELAXED, __HIP_MEMORY_SCOPE_AGENT);
  t.u[1] = __hip_atomic_load((const unsigned long long*)p + 1, __ATOMIC_RELAXED, __HIP_MEMORY_SCOPE_AGENT);
  return t.v;
}

// sc1 write-through dword store (no L2 allocation -> no weight eviction, no wbl2 needed).
__device__ __forceinline__ void st4_byp(short* p, unsigned v) {
  __hip_atomic_store((unsigned*)p, v, __ATOMIC_RELAXED, __HIP_MEMORY_SCOPE_AGENT);
}

// Tree grid barrier, 256 WGs all resident (1/CU). All cross-WG data is written
// with sc1 write-through stores, so release = s_waitcnt vmcnt(0) per wave.
__device__ __forceinline__ void grid_barrier(unsigned* bar, int wg, unsigned gen) {
  asm volatile("s_waitcnt vmcnt(0)" ::: "memory");  // all sc1 stores at LLC
  __syncthreads();
  if (threadIdx.x == 0) {
    unsigned* leaf = bar + (wg >> 4) * 32;
    unsigned prev = __hip_atomic_fetch_add(leaf, 1u, __ATOMIC_RELAXED, __HIP_MEMORY_SCOPE_AGENT);
    if (prev == gen * 16u - 1u) {
      unsigned rp = __hip_atomic_fetch_add(bar + BAR_ROOT, 1u, __ATOMIC_RELAXED, __HIP_MEMORY_SCOPE_AGENT);
      if (rp == gen * 16u - 1u) {
        __hip_atomic_store(bar + BAR_FLAG, gen, __ATOMIC_RELAXED, __HIP_MEMORY_SCOPE_AGENT);
      } else {
        while (__hip_atomic_load(bar + BAR_FLAG, __ATOMIC_RELAXED, __HIP_MEMORY_SCOPE_AGENT) < gen)
          __builtin_amdgcn_s_sleep(1);
      }
    } else {
      while (__hip_atomic_load(bar + BAR_FLAG, __ATOMIC_RELAXED, __HIP_MEMORY_SCOPE_AGENT) < gen)
        __builtin_amdgcn_s_sleep(1);
    }
  }
  __syncthreads();
}

// ---------------- pack: weights -> bf16 MFMA-fragment order, inputs -> bf16 ----------------
// W0P/W1P layout: [g:16][kb][c:16][512]; col of gates = fc*HH + g*64 + cb*16 + (l&15),
// fc = c&3 (gate), cb = c>>2 (channel sub-block); k = kb*32 + (l>>4)*8 + e.
__global__ void pack_all(
    const float* __restrict__ z, const float* __restrict__ tg,
    const float* __restrict__ Wih0, const float* __restrict__ Whh0,
    const float* __restrict__ Wih1, const float* __restrict__ Whh1,
    const float* __restrict__ Wz0, const float* __restrict__ Wz1,
    const float* __restrict__ Wp,
    short* __restrict__ W0P, short* __restrict__ W1P,
    short* __restrict__ WzP, short* __restrict__ WpP,
    short* __restrict__ zbf, short* __restrict__ Xbf)
{
  const int N0 = 16 * NKB0 * 16 * 64;  // 540672
  const int N1 = 16 * NKB1 * 16 * 64;  // 1048576
  const int N2 = 32 * NKBZ * 4 * 64;
  const int N3 = NKBP * 2 * 64;
  const int N4 = (BB * ZZ) / 8;
  const int N5 = (TT * BB * EE) / 8;
  const int TOT = N0 + N1 + N2 + N3 + N4 + N5;
  for (int idx = blockIdx.x * blockDim.x + threadIdx.x; idx < TOT;
       idx += gridDim.x * blockDim.x) {
    int j = idx;
    short8 ov;
    if (j < N0) {
      const int l = j & 63, c = (j >> 6) & 15, rest = j >> 10;
      const int kb = rest % NKB0, g = rest / NKB0;
      const int row = (c & 3) * HH + g * 64 + (c >> 2) * 16 + (l & 15);
      const int k0 = kb * 32 + ((l >> 4) * 8);
      #pragma unroll
      for (int i = 0; i < 8; ++i) {
        const int k = k0 + i;
        const float v = (k < HH) ? Whh0[(size_t)row * HH + k]
                                 : Wih0[(size_t)row * EE + (k - HH)];
        ov[i] = (short)f2bf(v);
      }
      *(short8*)(W0P + (size_t)j * 8) = ov;
      continue;
    }
    j -= N0;
    if (j < N1) {
      const int l = j & 63, c = (j >> 6) & 15, rest = j >> 10;
      const int kb = rest & 63, g = rest >> 6;
      const int row = (c & 3) * HH + g * 64 + (c >> 2) * 16 + (l & 15);
      const int k0 = kb * 32 + ((l >> 4) * 8);
      #pragma unroll
      for (int i = 0; i < 8; ++i) {
        const int k = k0 + i;
        const float v = (k < HH) ? Wih1[(size_t)row * HH + k]
                                 : Whh1[(size_t)row * HH + (k - HH)];
        ov[i] = (short)f2bf(v);
      }
      *(short8*)(W1P + (size_t)j * 8) = ov;
      continue;
    }
    j -= N1;
    if (j < N2) {
      const int l = j & 63, fc = (j >> 6) & 3, rest = j >> 8;
      const int kb = rest & 15, ct = rest >> 4;
      const int col = ct * 64 + fc * 16 + (l & 15);
      const int lay = col >> 10, ch = col & (HH - 1);
      const int k0 = kb * 32 + ((l >> 4) * 8);
      const float* W = lay ? Wz1 : Wz0;
      #pragma unroll
      for (int i = 0; i < 8; ++i) ov[i] = (short)f2bf(W[(size_t)ch * ZZ + k0 + i]);
      *(short8*)(WzP + (size_t)j * 8) = ov;
      continue;
    }
    j -= N2;
    if (j < N3) {
      const int l = j & 63, fc = (j >> 6) & 1, kb = j >> 7;
      const int e = fc * 16 + (l & 15);
      const int k0 = kb * 32 + ((l >> 4) * 8);
      #pragma unroll
      for (int i = 0; i < 8; ++i) ov[i] = (short)f2bf(Wp[(size_t)e * HH + k0 + i]);
      *(short8*)(WpP + (size_t)j * 8) = ov;
      continue;
    }
    j -= N3;
    if (j < N4) {
      #pragma unroll
      for (int i = 0; i < 8; ++i) ov[i] = (short)f2bf(z[(size_t)j * 8 + i]);
      *(short8*)(zbf + (size_t)j * 8) = ov;
      continue;
    }
    j -= N4;
    {
      const int base = j * 8;
      const int t = base >> 13, rem = base & 8191;
      if (t == 0) {
        #pragma unroll
        for (int i = 0; i < 8; ++i) ov[i] = 0;
      } else {
        #pragma unroll
        for (int i = 0; i < 8; ++i) ov[i] = (short)f2bf(tg[(size_t)(t - 1) * 8192 + rem + i]);
      }
      *(short8*)(Xbf + (size_t)j * 8) = ov;
    }
  }
}

// ---------------- init: h0/h1 = tanh(z @ Wz^T + bz), written in tiled h layout ----------------
__global__ void __launch_bounds__(256, 1)
init_h(const short* __restrict__ WzP, const short* __restrict__ zbf,
       const float* __restrict__ bz0, const float* __restrict__ bz1,
       short* __restrict__ H0s0, short* __restrict__ H1s0)
{
  __shared__ float red[2][64][66];
  const int wg = blockIdx.x;            // 128 = 4 btiles x 32 ctiles
  const int btile = (wg >> 5) * 64;
  const int ct = wg & 31;
  const int tid = threadIdx.x;
  const int wv = tid >> 6, ln = tid & 63;
  const int lr = ln & 15, lk = (ln >> 4) * 8, hi4 = (ln >> 4) * 4;

  f4 acc[4][4];
  #pragma unroll
  for (int r = 0; r < 4; ++r)
    #pragma unroll
    for (int c = 0; c < 4; ++c) acc[r][c] = (f4)0.0f;

  #pragma unroll 2
  for (int i = 0; i < 4; ++i) {
    const int kb = wv + i * 4;
    short8 av[4], bv[4];
    const short* ap = zbf + (size_t)(btile + lr) * ZZ + kb * 32 + lk;
    #pragma unroll
    for (int r = 0; r < 4; ++r) av[r] = ld16(ap + (size_t)r * 16 * ZZ);
    const short* bp = WzP + ((size_t)(ct * NKBZ + kb) * 4) * 512 + ln * 8;
    #pragma unroll
    for (int c = 0; c < 4; ++c) bv[c] = ld16(bp + (size_t)c * 512);
    #pragma unroll
    for (int r = 0; r < 4; ++r)
      #pragma unroll
      for (int c = 0; c < 4; ++c) acc[r][c] = mfma16(av[r], bv[c], acc[r][c]);
  }

  if (wv < 2) {
    #pragma unroll
    for (int r = 0; r < 4; ++r)
      #pragma unroll
      for (int c = 0; c < 4; ++c)
        #pragma unroll
        for (int q = 0; q < 4; ++q)
          red[wv][r * 16 + hi4 + q][c * 16 + lr] = acc[r][c][q];
  }
  __syncthreads();
  if (wv >= 2) {
    #pragma unroll
    for (int r = 0; r < 4; ++r)
      #pragma unroll
      for (int c = 0; c < 4; ++c)
        #pragma unroll
        for (int q = 0; q < 4; ++q)
          red[wv - 2][r * 16 + hi4 + q][c * 16 + lr] += acc[r][c][q];
  }
  __syncthreads();

  const int c2 = tid & 63, rr = tid >> 6;
  #pragma unroll
  for (int k = 0; k < 16; ++k) {
    const int r = rr + k * 4;
    const int cg = ct * 64 + c2;
    const int lay = cg >> 10, ch = cg & (HH - 1);
    const float v = tanh_f(red[0][r][c2] + red[1][r][c2] + (lay ? bz1[ch] : bz0[ch]));
    short* dst = lay ? H1s0 : H0s0;
    dst[(size_t)(ch >> 4) * (BB * 16) + (size_t)(btile + r) * 16 + (ch & 15)] = (short)f2bf(v);
  }
}

// ---------------- persistent sequential LSTM ----------------
// Tile = 16 rows x 256 gate-cols (g in [0,16) covers 64 h-channels x 4 gates).
// XCD-exact co-location: WG reads HW_REG_XCC_ID and claims a tile from its XCD's
// pool (XCD x owns col-groups {2x,2x+1} x 16 btiles = 32 tiles); two-phase
// deterministic overflow keeps exact cover under ANY dispatch distribution.
// Per-XCD weight set = 2 groups x 1.59 MB = 3.2 MB -> L2-resident.
// All h state: 2-slot ping-pong, sc1 bypass loads / write-through stores.
__global__ void __launch_bounds__(512, 1)
lstm_seq(const short* __restrict__ W0P, const short* __restrict__ W1P,
         const short* __restrict__ Xbf,
         short* __restrict__ H0pp, short* __restrict__ H1pp,
         float* __restrict__ C0, float* __restrict__ C1,
         short* __restrict__ H1arch,
         const float* __restrict__ bi0, const float* __restrict__ bh0,
         const float* __restrict__ bi1, const float* __restrict__ bh1,
         unsigned* __restrict__ bar)
{
  __shared__ float red[4][16][258];
  __shared__ int stile;
  const int wg = blockIdx.x;
  const int tid = threadIdx.x;
  const int wv = tid >> 6, ln = tid & 63;          // 8 waves, K-split-8
  const int lr = ln & 15, lk = (ln >> 4) * 8, hi4 = (ln >> 4) * 4;

  // ---- phase 1: claim a tile on this WG's own XCD ----
  if (tid == 0) {
    unsigned x;
    asm volatile("s_getreg_b32 %0, hwreg(HW_REG_XCC_ID)" : "=s"(x));
    x &= 7u;
    unsigned r = __hip_atomic_fetch_add(bar + BAR_CNT + x * 32, 1u,
                                        __ATOMIC_RELAXED, __HIP_MEMORY_SCOPE_AGENT);
    if (r < 32u) {
      stile = (int)(x * 32u + r);
    } else {
      unsigned o = __hip_atomic_fetch_add(bar + BAR_OVF, 1u,
                                          __ATOMIC_RELAXED, __HIP_MEMORY_SCOPE_AGENT);
      stile = -1 - (int)o;
    }
  }
  __syncthreads();
  int tile = stile;
  grid_barrier(bar, wg, 1);
  if (tile < 0) {  // phase 2: deterministic leftover assignment
    if (tid == 0) {
      int want = -1 - tile, tl = 0;
      for (int xx = 0; xx < 8; ++xx) {
        int c = (int)__hip_atomic_load(bar + BAR_CNT + xx * 32,
                                       __ATOMIC_RELAXED, __HIP_MEMORY_SCOPE_AGENT);
        if (c > 32) c = 32;
        const int d = 32 - c;
        if (want < d) { tl = xx * 32 + c + want; break; }
        want -= d;
      }
      stile = tl;
    }
    __syncthreads();
    tile = stile;
  }
  const int g = 2 * (tile >> 5) + (tile & 1);      // col-group 0..15
  const int btile = (tile >> 1) & 15;              // 16-row tile 0..15

  const int u2 = (tid & 31) * 2;                   // channel pair within 64
  const int erow = tid >> 5;                       // 0..15
  const int rowg = btile * 16 + erow;
  const int ch0 = g * 64 + u2;

  float bs0[2][4], bs1[2][4];
  #pragma unroll
  for (int p = 0; p < 2; ++p)
    #pragma unroll
    for (int gi = 0; gi < 4; ++gi) {
      bs0[p][gi] = bi0[gi * HH + ch0 + p] + bh0[gi * HH + ch0 + p];
      bs1[p][gi] = bi1[gi * HH + ch0 + p] + bh1[gi * HH + ch0 + p];
    }

  const short* W0w = W0P + (size_t)g * NKB0 * 16 * 512;
  const short* W1w = W1P + (size_t)g * NKB1 * 16 * 512;

  // per-lane A offset within an h slot for k-block kb: kb*2*4096 + aoff
  const int aoff = (lk >> 4) * (BB * 16) + (btile * 16 + lr) * 16 + (lk & 15);
  const size_t cbase = ((size_t)g * BB + rowg) * 64 + u2;                    // C index
  const size_t hoff = (size_t)(ch0 >> 4) * (BB * 16) + (size_t)rowg * 16 + (ch0 & 15);

  for (int t = 0; t < TT; ++t) {
    const short* h0in = H0pp + (size_t)(t & 1) * SLOTSH;
    short* h0out      = H0pp + (size_t)((t + 1) & 1) * SLOTSH;
    const short* h1in = H1pp + (size_t)(t & 1) * SLOTSH;
    short* h1out      = H1pp + (size_t)((t + 1) & 1) * SLOTSH;
    short* arch       = H1arch + (size_t)t * SLOTSH;

    // ===== GEMM0: gates0 = [h0 | x_t] @ W0^T, K-split over 8 waves =====
    f4 acc[16];
    #pragma unroll
    for (int c = 0; c < 16; ++c) acc[c] = (f4)0.0f;

    #pragma unroll
    for (int i = 0; i < 4; ++i) {
      const int kb = wv + 8 * i;        // 0..31 : h0 part
      const short8 av = ld16_byp(h0in + (size_t)kb * 2 * (BB * 16) + aoff);
      const short* bp = W0w + (size_t)(kb * 16) * 512 + ln * 8;
      short8 bv[16];
      #pragma unroll
      for (int c = 0; c < 16; ++c) bv[c] = ld16(bp + (size_t)c * 512);
      #pragma unroll
      for (int c = 0; c < 16; ++c) acc[c] = mfma16(av, bv[c], acc[c]);
    }
    if (wv == 0) {                      // kb = 32 : x_t part (row-major Xbf, static)
      const short8 av = ld16(Xbf + (size_t)((size_t)t * BB + btile * 16 + lr) * EE + lk);
      const short* bp = W0w + (size_t)(32 * 16) * 512 + ln * 8;
      short8 bv[16];
      #pragma unroll
      for (int c = 0; c < 16; ++c) bv[c] = ld16(bp + (size_t)c * 512);
      #pragma unroll
      for (int c = 0; c < 16; ++c) acc[c] = mfma16(av, bv[c], acc[c]);
    }

    if (wv < 4) {
      #pragma unroll
      for (int c = 0; c < 16; ++c)
        #pragma unroll
        for (int q = 0; q < 4; ++q)
          red[wv][hi4 + q][c * 16 + lr] = acc[c][q];
    }
    __syncthreads();
    if (wv >= 4) {
      #pragma unroll
      for (int c = 0; c < 16; ++c)
        #pragma unroll
        for (int q = 0; q < 4; ++q)
          red[wv - 4][hi4 + q][c * 16 + lr] += acc[c][q];
    }
    __syncthreads();

    // fused LSTM elementwise, layer 0 (2 channels per thread)
    {
      float2 cv = *(float2*)&C0[cbase];
      unsigned pv = 0;
      #pragma unroll
      for (int p = 0; p < 2; ++p) {
        const int w = u2 + p;
        const int cc = (w >> 4) * 4, uu = w & 15;
        float s[4];
        #pragma unroll
        for (int gi = 0; gi < 4; ++gi)
          s[gi] = red[0][erow][(cc + gi) * 16 + uu] + red[1][erow][(cc + gi) * 16 + uu]
                + red[2][erow][(cc + gi) * 16 + uu] + red[3][erow][(cc + gi) * 16 + uu]
                + bs0[p][gi];
        const float gi_ = sigm(s[0]), gf = sigm(s[1]);
        const float gg = tanh_f(s[2]), go = sigm(s[3]);
        const float cn = gf * (p ? cv.y : cv.x) + gi_ * gg;
        if (p) cv.y = cn; else cv.x = cn;
        pv |= ((unsigned)f2bf(go * tanh_f(cn))) << (16 * p);
      }
      *(float2*)&C0[cbase] = cv;
      st4_byp(h0out + hoff, pv);
    }

    grid_barrier(bar, wg, (unsigned)(t + 2));

    // ===== GEMM1: gates1 = [h0' | h1] @ W1^T =====
    #pragma unroll
    for (int c = 0; c < 16; ++c) acc[c] = (f4)0.0f;

    #pragma unroll
    for (int i = 0; i < 8; ++i) {
      const int kb = wv + 8 * i;
      const short* ap = (i < 4)
          ? (h0in = nullptr, h0out + (size_t)kb * 2 * (BB * 16) + aoff)
          : (h1in + (size_t)(kb - 32) * 2 * (BB * 16) + aoff);
      const short8 av = ld16_byp(ap);
      const short* bp = W1w + (size_t)(kb * 16) * 512 + ln * 8;
      short8 bv[16];
      #pragma unroll
      for (int c = 0; c < 16; ++c) bv[c] = ld16(bp + (size_t)c * 512);
      #pragma unroll
      for (int c = 0; c < 16; ++c) acc[c] = mfma16(av, bv[c], acc[c]);
    }

    if (wv < 4) {
      #pragma unroll
      for (int c = 0; c < 16; ++c)
        #pragma unroll
        for (int q = 0; q < 4; ++q)
          red[wv][hi4 + q][c * 16 + lr] = acc[c][q];
    }
    __syncthreads();
    if (wv >= 4) {
      #pragma unroll
      for (int c = 0; c < 16; ++c)
        #pragma unroll
        for (int q = 0; q < 4; ++q)
          red[wv - 4][hi4 + q][c * 16 + lr] += acc[c][q];
    }
    __syncthreads();

    // fused LSTM elementwise, layer 1 (+ archive)
    {
      float2 cv = *(float2*)&C1[cbase];
      unsigned pv = 0;
      #pragma unroll
      for (int p = 0; p < 2; ++p) {
        const int w = u2 + p;
        const int cc = (w >> 4) * 4, uu = w & 15;
        float s[4];
        #pragma unroll
        for (int gi = 0; gi < 4; ++gi)
          s[gi] = red[0][erow][(cc + gi) * 16 + uu] + red[1][erow][(cc + gi) * 16 + uu]
                + red[2][erow][(cc + gi) * 16 + uu] + red[3][erow][(cc + gi) * 16 + uu]
                + bs1[p][gi];
        const float gi_ = sigm(s[0]), gf = sigm(s[1]);
        const float gg = tanh_f(s[2]), go = sigm(s[3]);
        const float cn = gf * (p ? cv.y : cv.x) + gi_ * gg;
        if (p) cv.y = cn; else cv.x = cn;
        pv |= ((unsigned)f2bf(go * tanh_f(cn))) << (16 * p);
      }
      *(float2*)&C1[cbase] = cv;
      st4_byp(h1out + hoff, pv);
      st4_byp(arch + hoff, pv);
    }
    __syncthreads();   // protect `red` (next GEMM0 reduction) against stragglers
  }
}

// ---------------- final projection: out = H1arch @ Wp^T + bp ----------------
__global__ void __launch_bounds__(256, 1)
proj(const short* __restrict__ H1a, const short* __restrict__ WpP,
     const float* __restrict__ bp, float* __restrict__ out)
{
  __shared__ float red[2][64][34];
  const int rt = blockIdx.x * 64;       // 256 blocks over 16384 rows
  const int tslot = rt >> 8;            // all 64 rows share one t (64 | 256)
  const int rb = rt & 255;
  const int tid = threadIdx.x;
  const int wv = tid >> 6, ln = tid & 63;
  const int lr = ln & 15, lk = (ln >> 4) * 8, hi4 = (ln >> 4) * 4;

  const short* base = H1a + (size_t)tslot * SLOTSH;
  const int aoff = (lk >> 4) * (BB * 16) + (rb + lr) * 16 + (lk & 15);

  f4 acc[4][2];
  #pragma unroll
  for (int r = 0; r < 4; ++r)
    #pragma unroll
    for (int c = 0; c < 2; ++c) acc[r][c] = (f4)0.0f;

  #pragma unroll 2
  for (int i = 0; i < 8; ++i) {
    const int kb = wv + i * 4;          // < 32
    short8 av[4], bv[2];
    const short* ap = base + (size_t)kb * 2 * (BB * 16) + aoff;
    #pragma unroll
    for (int r = 0; r < 4; ++r) av[r] = ld16(ap + r * 256);
    const short* bq = WpP + (size_t)kb * 2 * 512 + ln * 8;
    #pragma unroll
    for (int c = 0; c < 2; ++c) bv[c] = ld16(bq + (size_t)c * 512);
    #pragma unroll
    for (int r = 0; r < 4; ++r)
      #pragma unroll
      for (int c = 0; c < 2; ++c) acc[r][c] = mfma16(av[r], bv[c], acc[r][c]);
  }

  if (wv < 2) {
    #pragma unroll
    for (int r = 0; r < 4; ++r)
      #pragma unroll
      for (int c = 0; c < 2; ++c)
        #pragma unroll
        for (int q = 0; q < 4; ++q)
          red[wv][r * 16 + hi4 + q][c * 16 + lr] = acc[r][c][q];
  }
  __syncthreads();
  if (wv >= 2) {
    #pragma unroll
    for (int r = 0; r < 4; ++r)
      #pragma unroll
      for (int c = 0; c < 2; ++c)
        #pragma unroll
        for (int q = 0; q < 4; ++q)
          red[wv - 2][r * 16 + hi4 + q][c * 16 + lr] += acc[r][c][q];
  }
  __syncthreads();

  const int ce = tid & 31, rr = tid >> 5;
  #pragma unroll
  for (int k = 0; k < 8; ++k) {
    const int r = rr + k * 8;
    out[(size_t)(rt + r) * EE + ce] = red[0][r][ce] + red[1][r][ce] + bp[ce];
  }
}

extern "C" void kernel_launch(void* const* d_in, const int* in_sizes, int n_in,
                              void* d_out, int out_size, void* d_ws, size_t ws_size,
                              hipStream_t stream) {
  const float* z    = (const float*)d_in[0];
  const float* tg   = (const float*)d_in[1];
  const float* Wih0 = (const float*)d_in[3];
  const float* Whh0 = (const float*)d_in[4];
  const float* bi0  = (const float*)d_in[5];
  const float* bh0  = (const float*)d_in[6];
  const float* Wih1 = (const float*)d_in[7];
  const float* Whh1 = (const float*)d_in[8];
  const float* bi1  = (const float*)d_in[9];
  const float* bh1  = (const float*)d_in[10];
  const float* Wz0  = (const float*)d_in[11];
  const float* bz0  = (const float*)d_in[12];
  const float* Wz1  = (const float*)d_in[13];
  const float* bz1  = (const float*)d_in[14];
  const float* Wp   = (const float*)d_in[15];
  const float* bpv  = (const float*)d_in[16];

  char* ws = (char*)d_ws;
  size_t off = 0;
  unsigned* bar = (unsigned*)(ws + off); off += 4096;
  short* W0P  = (short*)(ws + off); off += (size_t)16 * NKB0 * 16 * 512 * 2;
  short* W1P  = (short*)(ws + off); off += (size_t)16 * NKB1 * 16 * 512 * 2;
  short* WzP  = (short*)(ws + off); off += (size_t)32 * NKBZ * 4 * 512 * 2;
  short* WpP  = (short*)(ws + off); off += (size_t)NKBP * 2 * 512 * 2;
  short* zbf  = (short*)(ws + off); off += (size_t)BB * ZZ * 2;
  short* Xbf  = (short*)(ws + off); off += (size_t)TT * BB * EE * 2;
  float* C0   = (float*)(ws + off); off += (size_t)BB * HH * 4;
  float* C1   = (float*)(ws + off); off += (size_t)BB * HH * 4;
  short* H0pp = (short*)(ws + off); off += (size_t)2 * SLOTSH * 2;
  short* H1pp = (short*)(ws + off); off += (size_t)2 * SLOTSH * 2;
  short* H1a  = (short*)(ws + off); off += (size_t)TT * SLOTSH * 2;   // 33.5 MB

  if (ws_size < off) return;  // insufficient workspace -> fail loudly (zero output)

  hipMemsetAsync(bar, 0, 4096, stream);
  hipMemsetAsync(C0, 0, (size_t)2 * BB * HH * 4, stream);  // C0,C1 contiguous

  pack_all<<<dim3(1024), dim3(256), 0, stream>>>(z, tg, Wih0, Whh0, Wih1, Whh1,
                                                 Wz0, Wz1, Wp,
                                                 W0P, W1P, WzP, WpP, zbf, Xbf);
  init_h<<<dim3(128), dim3(256), 0, stream>>>(WzP, zbf, bz0, bz1, H0pp, H1pp);
  lstm_seq<<<dim3(256), dim3(512), 0, stream>>>(W0P, W1P, Xbf, H0pp, H1pp,
                                                C0, C1, H1a, bi0, bh0, bi1, bh1, bar);
  proj<<<dim3(256), dim3(256), 0, stream>>>(H1a, WpP, bpv, (float*)d_out);
}

// Round 6
// 1352.746 us; speedup vs baseline: 4.1327x; 4.1327x over previous
//
#include <hip/hip_runtime.h>

#define TT 64
#define BB 256
#define HH 1024
#define ZZ 512
#define EE 32

#define NKB0 33   // K=1056 in 32-deep blocks (layer0: h 32 blocks + x 1 block)
#define NKB1 64   // K=2048
#define NKBZ 16   // K=512
#define NKBP 32   // K=1024

#define SLOTSH ((size_t)(HH / 16) * BB * 16)   // shorts per tiled h slot = 262144 (512 KB)

#define BAR_ROOT (16 * 32)
#define BAR_FLAG (17 * 32)

typedef __attribute__((ext_vector_type(8))) short short8;
typedef __attribute__((ext_vector_type(4))) float f4;

__device__ __forceinline__ f4 mfma16(short8 a, short8 b, f4 c) {
  return __builtin_amdgcn_mfma_f32_16x16x32_bf16(a, b, c, 0, 0, 0);
}

__device__ __forceinline__ unsigned short f2bf(float f) {
  unsigned u = __builtin_bit_cast(unsigned, f);
  u = u + 0x7fffu + ((u >> 16) & 1u);   // RNE; inputs are finite
  return (unsigned short)(u >> 16);
}

__device__ __forceinline__ float sigm(float x) { return 1.0f / (1.0f + __expf(-x)); }
__device__ __forceinline__ float tanh_f(float x) { return 1.0f - 2.0f / (__expf(2.0f * x) + 1.0f); }

__device__ __forceinline__ short8 ld16(const short* p) { return *(const short8*)p; }

// Agent-scope relaxed 16B load as 2x8B atomics -> global_load_dwordx2 sc1
// (L2-bypass, device-coherent, vmcnt-tracked so the compiler can pipeline it).
__device__ __forceinline__ short8 ld16_byp(const short* p) {
  union { unsigned long long u[2]; short8 v; } t;
  t.u[0] = __hip_atomic_load((const unsigned long long*)p, __ATOMIC_RELAXED, __HIP_MEMORY_SCOPE_AGENT);
  t.u[1] = __hip_atomic_load((const unsigned long long*)p + 1, __ATOMIC_RELAXED, __HIP_MEMORY_SCOPE_AGENT);
  return t.v;
}

// sc1 write-through dword store (no L2 dirty allocation -> no wbl2 needed; value
// is at LLC once vmcnt retires -- mechanism validated by R4).
__device__ __forceinline__ void st4_byp(short* p, unsigned v) {
  __hip_atomic_store((unsigned*)p, v, __ATOMIC_RELAXED, __HIP_MEMORY_SCOPE_AGENT);
}

// Tree grid barrier, 256 WGs all resident (1/CU). All cross-WG data is written
// with sc1 write-through stores, so release = s_waitcnt vmcnt(0) per wave.
__device__ __forceinline__ void grid_barrier(unsigned* bar, int wg, unsigned gen) {
  asm volatile("s_waitcnt vmcnt(0)" ::: "memory");  // all sc1 stores at LLC
  __syncthreads();
  if (threadIdx.x == 0) {
    unsigned* leaf = bar + (wg >> 4) * 32;
    unsigned prev = __hip_atomic_fetch_add(leaf, 1u, __ATOMIC_RELAXED, __HIP_MEMORY_SCOPE_AGENT);
    if (prev == gen * 16u - 1u) {
      unsigned rp = __hip_atomic_fetch_add(bar + BAR_ROOT, 1u, __ATOMIC_RELAXED, __HIP_MEMORY_SCOPE_AGENT);
      if (rp == gen * 16u - 1u) {
        __hip_atomic_store(bar + BAR_FLAG, gen, __ATOMIC_RELAXED, __HIP_MEMORY_SCOPE_AGENT);
      } else {
        while (__hip_atomic_load(bar + BAR_FLAG, __ATOMIC_RELAXED, __HIP_MEMORY_SCOPE_AGENT) < gen)
          __builtin_amdgcn_s_sleep(1);
      }
    } else {
      while (__hip_atomic_load(bar + BAR_FLAG, __ATOMIC_RELAXED, __HIP_MEMORY_SCOPE_AGENT) < gen)
        __builtin_amdgcn_s_sleep(1);
    }
  }
  __syncthreads();
}

// ---------------- pack: weights -> bf16 MFMA-fragment order, inputs -> bf16 ----------------
__global__ void pack_all(
    const float* __restrict__ z, const float* __restrict__ tg,
    const float* __restrict__ Wih0, const float* __restrict__ Whh0,
    const float* __restrict__ Wih1, const float* __restrict__ Whh1,
    const float* __restrict__ Wz0, const float* __restrict__ Wz1,
    const float* __restrict__ Wp,
    short* __restrict__ W0P, short* __restrict__ W1P,
    short* __restrict__ WzP, short* __restrict__ WpP,
    short* __restrict__ zbf, short* __restrict__ Xbf)
{
  const int N0 = 64 * NKB0 * 4 * 64;
  const int N1 = 64 * NKB1 * 4 * 64;
  const int N2 = 32 * NKBZ * 4 * 64;
  const int N3 = NKBP * 2 * 64;
  const int N4 = (BB * ZZ) / 8;
  const int N5 = (TT * BB * EE) / 8;
  const int TOT = N0 + N1 + N2 + N3 + N4 + N5;
  for (int idx = blockIdx.x * blockDim.x + threadIdx.x; idx < TOT;
       idx += gridDim.x * blockDim.x) {
    int j = idx;
    short8 ov;
    if (j < N0) {
      const int l = j & 63, fc = (j >> 6) & 3, rest = j >> 8;
      const int kb = rest % NKB0, jt = rest / NKB0;
      const int row = fc * HH + jt * 16 + (l & 15);
      const int k0 = kb * 32 + ((l >> 4) * 8);
      #pragma unroll
      for (int i = 0; i < 8; ++i) {
        const int k = k0 + i;
        const float v = (k < HH) ? Whh0[(size_t)row * HH + k]
                                 : Wih0[(size_t)row * EE + (k - HH)];
        ov[i] = (short)f2bf(v);
      }
      *(short8*)(W0P + (size_t)j * 8) = ov;
      continue;
    }
    j -= N0;
    if (j < N1) {
      const int l = j & 63, fc = (j >> 6) & 3, rest = j >> 8;
      const int kb = rest & 63, jt = rest >> 6;
      const int row = fc * HH + jt * 16 + (l & 15);
      const int k0 = kb * 32 + ((l >> 4) * 8);
      #pragma unroll
      for (int i = 0; i < 8; ++i) {
        const int k = k0 + i;
        const float v = (k < HH) ? Wih1[(size_t)row * HH + k]
                                 : Whh1[(size_t)row * HH + (k - HH)];
        ov[i] = (short)f2bf(v);
      }
      *(short8*)(W1P + (size_t)j * 8) = ov;
      continue;
    }
    j -= N1;
    if (j < N2) {
      const int l = j & 63, fc = (j >> 6) & 3, rest = j >> 8;
      const int kb = rest & 15, ct = rest >> 4;
      const int col = ct * 64 + fc * 16 + (l & 15);
      const int lay = col >> 10, ch = col & (HH - 1);
      const int k0 = kb * 32 + ((l >> 4) * 8);
      const float* W = lay ? Wz1 : Wz0;
      #pragma unroll
      for (int i = 0; i < 8; ++i) ov[i] = (short)f2bf(W[(size_t)ch * ZZ + k0 + i]);
      *(short8*)(WzP + (size_t)j * 8) = ov;
      continue;
    }
    j -= N2;
    if (j < N3) {
      const int l = j & 63, fc = (j >> 6) & 1, kb = j >> 7;
      const int e = fc * 16 + (l & 15);
      const int k0 = kb * 32 + ((l >> 4) * 8);
      #pragma unroll
      for (int i = 0; i < 8; ++i) ov[i] = (short)f2bf(Wp[(size_t)e * HH + k0 + i]);
      *(short8*)(WpP + (size_t)j * 8) = ov;
      continue;
    }
    j -= N3;
    if (j < N4) {
      #pragma unroll
      for (int i = 0; i < 8; ++i) ov[i] = (short)f2bf(z[(size_t)j * 8 + i]);
      *(short8*)(zbf + (size_t)j * 8) = ov;
      continue;
    }
    j -= N4;
    {
      const int base = j * 8;
      const int t = base >> 13, rem = base & 8191;
      if (t == 0) {
        #pragma unroll
        for (int i = 0; i < 8; ++i) ov[i] = 0;
      } else {
        #pragma unroll
        for (int i = 0; i < 8; ++i) ov[i] = (short)f2bf(tg[(size_t)(t - 1) * 8192 + rem + i]);
      }
      *(short8*)(Xbf + (size_t)j * 8) = ov;
    }
  }
}

// ---------------- init: h0/h1 = tanh(z @ Wz^T + bz), written in tiled h layout ----------------
__global__ void __launch_bounds__(256, 1)
init_h(const short* __restrict__ WzP, const short* __restrict__ zbf,
       const float* __restrict__ bz0, const float* __restrict__ bz1,
       short* __restrict__ H0s0, short* __restrict__ H1s0)
{
  __shared__ float red[2][64][66];
  const int wg = blockIdx.x;            // 128 = 4 btiles x 32 ctiles
  const int btile = (wg >> 5) * 64;
  const int ct = wg & 31;
  const int tid = threadIdx.x;
  const int wv = tid >> 6, ln = tid & 63;
  const int lr = ln & 15, lk = (ln >> 4) * 8, hi4 = (ln >> 4) * 4;

  f4 acc[4][4];
  #pragma unroll
  for (int r = 0; r < 4; ++r)
    #pragma unroll
    for (int c = 0; c < 4; ++c) acc[r][c] = (f4)0.0f;

  #pragma unroll 2
  for (int i = 0; i < 4; ++i) {
    const int kb = wv + i * 4;
    short8 av[4], bv[4];
    const short* ap = zbf + (size_t)(btile + lr) * ZZ + kb * 32 + lk;
    #pragma unroll
    for (int r = 0; r < 4; ++r) av[r] = ld16(ap + (size_t)r * 16 * ZZ);
    const short* bp = WzP + ((size_t)(ct * NKBZ + kb) * 4) * 512 + ln * 8;
    #pragma unroll
    for (int c = 0; c < 4; ++c) bv[c] = ld16(bp + (size_t)c * 512);
    #pragma unroll
    for (int r = 0; r < 4; ++r)
      #pragma unroll
      for (int c = 0; c < 4; ++c) acc[r][c] = mfma16(av[r], bv[c], acc[r][c]);
  }

  if (wv < 2) {
    #pragma unroll
    for (int r = 0; r < 4; ++r)
      #pragma unroll
      for (int c = 0; c < 4; ++c)
        #pragma unroll
        for (int q = 0; q < 4; ++q)
          red[wv][r * 16 + hi4 + q][c * 16 + lr] = acc[r][c][q];
  }
  __syncthreads();
  if (wv >= 2) {
    #pragma unroll
    for (int r = 0; r < 4; ++r)
      #pragma unroll
      for (int c = 0; c < 4; ++c)
        #pragma unroll
        for (int q = 0; q < 4; ++q)
          red[wv - 2][r * 16 + hi4 + q][c * 16 + lr] += acc[r][c][q];
  }
  __syncthreads();

  const int c2 = tid & 63, rr = tid >> 6;
  #pragma unroll
  for (int k = 0; k < 16; ++k) {
    const int r = rr + k * 4;
    const int cg = ct * 64 + c2;
    const int lay = cg >> 10, ch = cg & (HH - 1);
    const float v = tanh_f(red[0][r][c2] + red[1][r][c2] + (lay ? bz1[ch] : bz0[ch]));
    short* dst = lay ? H1s0 : H0s0;
    dst[(size_t)(ch >> 4) * (BB * 16) + (size_t)(btile + r) * 16 + (ch & 15)] = (short)f2bf(v);
  }
}

// ---------------- persistent sequential LSTM ----------------
// h layout (per slot): [H/16 col-tiles][B rows][16 cols] bf16.
// BIG=true : h0/h1 are 65-slot sequences (fresh addresses every step). Reads are
//   NORMAL CACHED loads -> each h line is fetched once per XCD from LLC and then
//   served to all co-XCD WGs out of L2 (A dedup 64x -> ~8x). No staleness: each
//   address is written exactly once (sc1 write-through, at LLC before the tree
//   barrier) and never re-written. h1seq doubles as the archive.
// BIG=false: exact R4 behavior (2-slot ping-pong, sc1 bypass loads).
template <bool BIG>
__global__ void __launch_bounds__(512, 1)
lstm_seq(const short* __restrict__ W0P, const short* __restrict__ W1P,
         const short* __restrict__ Xbf,
         short* __restrict__ H0, short* __restrict__ H1,
         float* __restrict__ C0, float* __restrict__ C1,
         short* __restrict__ H1a,
         const float* __restrict__ bi0, const float* __restrict__ bh0,
         const float* __restrict__ bi1, const float* __restrict__ bh1,
         unsigned* __restrict__ bar)
{
  __shared__ float red[4][64][66];
  const int wg = blockIdx.x;            // 256 WGs
  const int x = wg & 7;
  const int q = wg >> 3;
  const int jt = x + 8 * (q & 7);
  const int btile = (q >> 3) * 64;
  const int tid = threadIdx.x;
  const int wv = tid >> 6, ln = tid & 63;          // 8 waves, K-split-8
  const int lr = ln & 15, lk = (ln >> 4) * 8, hi4 = (ln >> 4) * 4;

  const int u = tid & 15;
  const int rbase = tid >> 4;           // 0..31
  const int colg = jt * 16 + u;

  float bs0[4], bs1[4];
  #pragma unroll
  for (int g = 0; g < 4; ++g) {
    bs0[g] = bi0[g * HH + colg] + bh0[g * HH + colg];
    bs1[g] = bi1[g * HH + colg] + bh1[g * HH + colg];
  }

  const short* W0w = W0P + (size_t)jt * NKB0 * 4 * 512;
  const short* W1w = W1P + (size_t)jt * NKB1 * 4 * 512;

  // per-lane A offset within an h slot for k-block kb: slot + kb*2*4096 + aoff (+ r*256)
  const int aoff = (lk >> 4) * (BB * 16) + (btile + lr) * 16 + (lk & 15);
  const size_t ewi = (size_t)jt * (BB * 16) + u;   // elementwise tiled base

  for (int t = 0; t < TT; ++t) {
    const short* h0in = H0 + (size_t)(BIG ? t : (t & 1)) * SLOTSH;
    short* h0out      = H0 + (size_t)(BIG ? (t + 1) : ((t + 1) & 1)) * SLOTSH;
    const short* h1in = H1 + (size_t)(BIG ? t : (t & 1)) * SLOTSH;
    short* h1out      = H1 + (size_t)(BIG ? (t + 1) : ((t + 1) & 1)) * SLOTSH;
    short* arch       = BIG ? h1out : (H1a + (size_t)t * SLOTSH);

    // ===== GEMM0: gates0 = [h0 | x_t] @ W0^T, K-split over 8 waves =====
    f4 acc[4][4];
    #pragma unroll
    for (int r = 0; r < 4; ++r)
      #pragma unroll
      for (int c = 0; c < 4; ++c) acc[r][c] = (f4)0.0f;

    #pragma unroll
    for (int i = 0; i < 4; ++i) {
      const int kb = wv + 8 * i;        // 0..31 : h0 part
      short8 av[4], bv[4];
      const short* ap = h0in + (size_t)kb * 2 * (BB * 16) + aoff;
      #pragma unroll
      for (int r = 0; r < 4; ++r)
        av[r] = BIG ? ld16(ap + r * 256) : ld16_byp(ap + r * 256);
      const short* bp = W0w + (size_t)kb * 4 * 512 + ln * 8;
      #pragma unroll
      for (int c = 0; c < 4; ++c) bv[c] = ld16(bp + (size_t)c * 512);
      #pragma unroll
      for (int r = 0; r < 4; ++r)
        #pragma unroll
        for (int c = 0; c < 4; ++c) acc[r][c] = mfma16(av[r], bv[c], acc[r][c]);
    }
    if (wv == 0) {                      // kb = 32 : x_t part (row-major Xbf, static)
      short8 av[4], bv[4];
      const short* ap = Xbf + (size_t)((size_t)t * BB + btile + lr) * EE + lk;
      #pragma unroll
      for (int r = 0; r < 4; ++r) av[r] = ld16(ap + (size_t)r * 16 * EE);
      const short* bp = W0w + (size_t)32 * 4 * 512 + ln * 8;
      #pragma unroll
      for (int c = 0; c < 4; ++c) bv[c] = ld16(bp + (size_t)c * 512);
      #pragma unroll
      for (int r = 0; r < 4; ++r)
        #pragma unroll
        for (int c = 0; c < 4; ++c) acc[r][c] = mfma16(av[r], bv[c], acc[r][c]);
    }

    if (wv < 4) {
      #pragma unroll
      for (int r = 0; r < 4; ++r)
        #pragma unroll
        for (int c = 0; c < 4; ++c)
          #pragma unroll
          for (int q2 = 0; q2 < 4; ++q2)
            red[wv][r * 16 + hi4 + q2][c * 16 + lr] = acc[r][c][q2];
    }
    __syncthreads();
    if (wv >= 4) {
      #pragma unroll
      for (int r = 0; r < 4; ++r)
        #pragma unroll
        for (int c = 0; c < 4; ++c)
          #pragma unroll
          for (int q2 = 0; q2 < 4; ++q2)
            red[wv - 4][r * 16 + hi4 + q2][c * 16 + lr] += acc[r][c][q2];
    }
    __syncthreads();

    // fused LSTM elementwise, layer 0 (C tiled, WG-private, cached)
    #pragma unroll
    for (int k = 0; k < 2; ++k) {
      const int r = rbase + 32 * k;
      float s[4];
      #pragma unroll
      for (int g = 0; g < 4; ++g)
        s[g] = red[0][r][g * 16 + u] + red[1][r][g * 16 + u]
             + red[2][r][g * 16 + u] + red[3][r][g * 16 + u] + bs0[g];
      const float gi = sigm(s[0]), gf = sigm(s[1]);
      const float gg = tanh_f(s[2]), go = sigm(s[3]);
      const size_t ci = ewi + (size_t)(btile + r) * 16;
      const float cn = gf * C0[ci] + gi * gg;
      C0[ci] = cn;
      const unsigned hv = (unsigned)f2bf(go * tanh_f(cn));
      const unsigned ov = (unsigned)__shfl_xor((int)hv, 1, 64);
      if ((tid & 1) == 0) st4_byp(h0out + ci, hv | (ov << 16));
    }

    grid_barrier(bar, wg, (unsigned)(t + 1));

    // ===== GEMM1: gates1 = [h0' | h1] @ W1^T =====
    #pragma unroll
    for (int r = 0; r < 4; ++r)
      #pragma unroll
      for (int c = 0; c < 4; ++c) acc[r][c] = (f4)0.0f;

    #pragma unroll
    for (int i = 0; i < 4; ++i) {       // kb = wv+8i in [0,32): h0' part
      const int kb = wv + 8 * i;
      short8 av[4], bv[4];
      const short* ap = h0out + (size_t)kb * 2 * (BB * 16) + aoff;
      #pragma unroll
      for (int r = 0; r < 4; ++r)
        av[r] = BIG ? ld16(ap + r * 256) : ld16_byp(ap + r * 256);
      const short* bp = W1w + (size_t)kb * 4 * 512 + ln * 8;
      #pragma unroll
      for (int c = 0; c < 4; ++c) bv[c] = ld16(bp + (size_t)c * 512);
      #pragma unroll
      for (int r = 0; r < 4; ++r)
        #pragma unroll
        for (int c = 0; c < 4; ++c) acc[r][c] = mfma16(av[r], bv[c], acc[r][c]);
    }
    #pragma unroll
    for (int i = 4; i < 8; ++i) {       // kb in [32,64): h1 part
      const int kb = wv + 8 * i;
      short8 av[4], bv[4];
      const short* ap = h1in + (size_t)(kb - 32) * 2 * (BB * 16) + aoff;
      #pragma unroll
      for (int r = 0; r < 4; ++r)
        av[r] = BIG ? ld16(ap + r * 256) : ld16_byp(ap + r * 256);
      const short* bp = W1w + (size_t)kb * 4 * 512 + ln * 8;
      #pragma unroll
      for (int c = 0; c < 4; ++c) bv[c] = ld16(bp + (size_t)c * 512);
      #pragma unroll
      for (int r = 0; r < 4; ++r)
        #pragma unroll
        for (int c = 0; c < 4; ++c) acc[r][c] = mfma16(av[r], bv[c], acc[r][c]);
    }

    if (wv < 4) {
      #pragma unroll
      for (int r = 0; r < 4; ++r)
        #pragma unroll
        for (int c = 0; c < 4; ++c)
          #pragma unroll
          for (int q2 = 0; q2 < 4; ++q2)
            red[wv][r * 16 + hi4 + q2][c * 16 + lr] = acc[r][c][q2];
    }
    __syncthreads();
    if (wv >= 4) {
      #pragma unroll
      for (int r = 0; r < 4; ++r)
        #pragma unroll
        for (int c = 0; c < 4; ++c)
          #pragma unroll
          for (int q2 = 0; q2 < 4; ++q2)
            red[wv - 4][r * 16 + hi4 + q2][c * 16 + lr] += acc[r][c][q2];
    }
    __syncthreads();

    // fused LSTM elementwise, layer 1 (+ archive; BIG: h1out IS the archive slot)
    #pragma unroll
    for (int k = 0; k < 2; ++k) {
      const int r = rbase + 32 * k;
      float s[4];
      #pragma unroll
      for (int g = 0; g < 4; ++g)
        s[g] = red[0][r][g * 16 + u] + red[1][r][g * 16 + u]
             + red[2][r][g * 16 + u] + red[3][r][g * 16 + u] + bs1[g];
      const float gi = sigm(s[0]), gf = sigm(s[1]);
      const float gg = tanh_f(s[2]), go = sigm(s[3]);
      const size_t ci = ewi + (size_t)(btile + r) * 16;
      const float cn = gf * C1[ci] + gi * gg;
      C1[ci] = cn;
      const unsigned hv = (unsigned)f2bf(go * tanh_f(cn));
      const unsigned ov = (unsigned)__shfl_xor((int)hv, 1, 64);
      if ((tid & 1) == 0) {
        const unsigned pv = hv | (ov << 16);
        st4_byp(h1out + ci, pv);
        if (!BIG) st4_byp(arch + ci, pv);
      }
    }
    __syncthreads();   // protect `red` (next GEMM0 reduction) against stragglers
  }
}

// ---------------- final projection: out = H1 archive @ Wp^T + bp ----------------
__global__ void __launch_bounds__(256, 1)
proj(const short* __restrict__ H1a, const short* __restrict__ WpP,
     const float* __restrict__ bp, float* __restrict__ out)
{
  __shared__ float red[2][64][34];
  const int rt = blockIdx.x * 64;       // 256 blocks over 16384 rows
  const int tslot = rt >> 8;            // all 64 rows share one t (64 | 256)
  const int rb = rt & 255;
  const int tid = threadIdx.x;
  const int wv = tid >> 6, ln = tid & 63;
  const int lr = ln & 15, lk = (ln >> 4) * 8, hi4 = (ln >> 4) * 4;

  const short* base = H1a + (size_t)tslot * SLOTSH;
  const int aoff = (lk >> 4) * (BB * 16) + (rb + lr) * 16 + (lk & 15);

  f4 acc[4][2];
  #pragma unroll
  for (int r = 0; r < 4; ++r)
    #pragma unroll
    for (int c = 0; c < 2; ++c) acc[r][c] = (f4)0.0f;

  #pragma unroll 2
  for (int i = 0; i < 8; ++i) {
    const int kb = wv + i * 4;          // < 32
    short8 av[4], bv[2];
    const short* ap = base + (size_t)kb * 2 * (BB * 16) + aoff;
    #pragma unroll
    for (int r = 0; r < 4; ++r) av[r] = ld16(ap + r * 256);
    const short* bq = WpP + (size_t)kb * 2 * 512 + ln * 8;
    #pragma unroll
    for (int c = 0; c < 2; ++c) bv[c] = ld16(bq + (size_t)c * 512);
    #pragma unroll
    for (int r = 0; r < 4; ++r)
      #pragma unroll
      for (int c = 0; c < 2; ++c) acc[r][c] = mfma16(av[r], bv[c], acc[r][c]);
  }

  if (wv < 2) {
    #pragma unroll
    for (int r = 0; r < 4; ++r)
      #pragma unroll
      for (int c = 0; c < 2; ++c)
        #pragma unroll
        for (int q = 0; q < 4; ++q)
          red[wv][r * 16 + hi4 + q][c * 16 + lr] = acc[r][c][q];
  }
  __syncthreads();
  if (wv >= 2) {
    #pragma unroll
    for (int r = 0; r < 4; ++r)
      #pragma unroll
      for (int c = 0; c < 2; ++c)
        #pragma unroll
        for (int q = 0; q < 4; ++q)
          red[wv - 2][r * 16 + hi4 + q][c * 16 + lr] += acc[r][c][q];
  }
  __syncthreads();

  const int ce = tid & 31, rr = tid >> 5;
  #pragma unroll
  for (int k = 0; k < 8; ++k) {
    const int r = rr + k * 8;
    out[(size_t)(rt + r) * EE + ce] = red[0][r][ce] + red[1][r][ce] + bp[ce];
  }
}

extern "C" void kernel_launch(void* const* d_in, const int* in_sizes, int n_in,
                              void* d_out, int out_size, void* d_ws, size_t ws_size,
                              hipStream_t stream) {
  const float* z    = (const float*)d_in[0];
  const float* tg   = (const float*)d_in[1];
  const float* Wih0 = (const float*)d_in[3];
  const float* Whh0 = (const float*)d_in[4];
  const float* bi0  = (const float*)d_in[5];
  const float* bh0  = (const float*)d_in[6];
  const float* Wih1 = (const float*)d_in[7];
  const float* Whh1 = (const float*)d_in[8];
  const float* bi1  = (const float*)d_in[9];
  const float* bh1  = (const float*)d_in[10];
  const float* Wz0  = (const float*)d_in[11];
  const float* bz0  = (const float*)d_in[12];
  const float* Wz1  = (const float*)d_in[13];
  const float* bz1  = (const float*)d_in[14];
  const float* Wp   = (const float*)d_in[15];
  const float* bpv  = (const float*)d_in[16];

  char* ws = (char*)d_ws;
  size_t off = 0;
  unsigned* bar = (unsigned*)(ws + off); off += 4096;
  short* W0P  = (short*)(ws + off); off += (size_t)64 * NKB0 * 4 * 512 * 2;
  short* W1P  = (short*)(ws + off); off += (size_t)64 * NKB1 * 4 * 512 * 2;
  short* WzP  = (short*)(ws + off); off += (size_t)32 * NKBZ * 4 * 512 * 2;
  short* WpP  = (short*)(ws + off); off += (size_t)NKBP * 2 * 512 * 2;
  short* zbf  = (short*)(ws + off); off += (size_t)BB * ZZ * 2;
  short* Xbf  = (short*)(ws + off); off += (size_t)TT * BB * EE * 2;
  float* C0   = (float*)(ws + off); off += (size_t)BB * HH * 4;
  float* C1   = (float*)(ws + off); off += (size_t)BB * HH * 4;

  // BIG layout: H0seq (65 slots) + H1seq (65 slots, slots 1..64 = archive)
  const size_t seqB = (size_t)(TT + 1) * SLOTSH * 2;   // 34,078,720
  const size_t need_big = off + 2 * seqB;              // ~99.2 MB
  // small layout: H0pp(2) + H1pp(2) + H1a(64)
  const size_t need_small = off + 2 * ((size_t)2 * SLOTSH * 2) + (size_t)TT * SLOTSH * 2;
  const bool big = (ws_size >= need_big);

  if (ws_size < need_small) return;  // insufficient workspace -> fail loudly

  hipMemsetAsync(bar, 0, 4096, stream);
  hipMemsetAsync(C0, 0, (size_t)2 * BB * HH * 4, stream);  // C0,C1 contiguous

  pack_all<<<dim3(1024), dim3(256), 0, stream>>>(z, tg, Wih0, Whh0, Wih1, Whh1,
                                                 Wz0, Wz1, Wp,
                                                 W0P, W1P, WzP, WpP, zbf, Xbf);
  if (big) {
    short* H0seq = (short*)(ws + off);
    short* H1seq = (short*)(ws + off + seqB);
    init_h<<<dim3(128), dim3(256), 0, stream>>>(WzP, zbf, bz0, bz1, H0seq, H1seq);
    lstm_seq<true><<<dim3(256), dim3(512), 0, stream>>>(W0P, W1P, Xbf, H0seq, H1seq,
                                                        C0, C1, (short*)nullptr,
                                                        bi0, bh0, bi1, bh1, bar);
    proj<<<dim3(256), dim3(256), 0, stream>>>(H1seq + SLOTSH, WpP, bpv, (float*)d_out);
  } else {
    short* H0pp = (short*)(ws + off);
    short* H1pp = H0pp + 2 * SLOTSH;
    short* H1a  = H1pp + 2 * SLOTSH;
    init_h<<<dim3(128), dim3(256), 0, stream>>>(WzP, zbf, bz0, bz1, H0pp, H1pp);
    lstm_seq<false><<<dim3(256), dim3(512), 0, stream>>>(W0P, W1P, Xbf, H0pp, H1pp,
                                                         C0, C1, H1a,
                                                         bi0, bh0, bi1, bh1, bar);
    proj<<<dim3(256), dim3(256), 0, stream>>>(H1a, WpP, bpv, (float*)d_out);
  }
}